// Round 1
// baseline (300.082 us; speedup 1.0000x reference)
//
#include <hip/hip_runtime.h>

#define NN 50000
#define NE 800000

static __device__ __forceinline__ float bf2f(unsigned short h){
  union { unsigned u; float f; } c; c.u = ((unsigned)h) << 16; return c.f;
}
static __device__ __forceinline__ unsigned short f2bf(float f){
  union { float f; unsigned u; } c; c.f = f;
  unsigned u = c.u;
  return (unsigned short)((u + 0x7fffu + ((u >> 16) & 1u)) >> 16);
}

__global__ void k_zero(int* __restrict__ cnt){
  int i = blockIdx.x * 256 + threadIdx.x;
  if (i < NN) cnt[i] = 0;
}

__global__ void k_count(const int* __restrict__ dst, int* __restrict__ cnt){
  int e = blockIdx.x * 256 + threadIdx.x;
  if (e < NE) atomicAdd(&cnt[dst[e]], 1);
}

// per-block exclusive scan of 256-chunk; write block totals
__global__ void k_scan1(const int* __restrict__ cnt, int* __restrict__ partial,
                        int* __restrict__ blocksum){
  __shared__ int sm[256];
  int t = threadIdx.x;
  int i = blockIdx.x * 256 + t;
  int v = (i < NN) ? cnt[i] : 0;
  sm[t] = v;
  __syncthreads();
  #pragma unroll
  for (int off = 1; off < 256; off <<= 1){
    int x = (t >= off) ? sm[t - off] : 0;
    __syncthreads();
    sm[t] += x;
    __syncthreads();
  }
  if (i < NN) partial[i] = sm[t] - v;   // exclusive within block
  if (t == 255) blocksum[blockIdx.x] = sm[255];
}

__global__ void k_scan2(int* __restrict__ blocksum, int nb){
  __shared__ int sm[256];
  int t = threadIdx.x;
  int v = (t < nb) ? blocksum[t] : 0;
  sm[t] = v;
  __syncthreads();
  #pragma unroll
  for (int off = 1; off < 256; off <<= 1){
    int x = (t >= off) ? sm[t - off] : 0;
    __syncthreads();
    sm[t] += x;
    __syncthreads();
  }
  blocksum[t] = sm[t] - v;              // exclusive block offsets
}

__global__ void k_scan3(const int* __restrict__ cnt, const int* __restrict__ partial,
                        const int* __restrict__ blocksum, int* __restrict__ rowstart,
                        int* __restrict__ cursor, float* __restrict__ dis){
  int i = blockIdx.x * 256 + threadIdx.x;
  if (i >= NN) return;
  int s = partial[i] + blocksum[blockIdx.x];
  rowstart[i] = s;
  cursor[i] = s;
  dis[i] = rsqrtf((float)cnt[i] + 1.0f);
}

__global__ void k_fill(const int* __restrict__ src, const int* __restrict__ dst,
                       int* __restrict__ cursor, int* __restrict__ csr){
  int e = blockIdx.x * 256 + threadIdx.x;
  if (e >= NE) return;
  int d = dst[e];
  int pos = atomicAdd(&cursor[d], 1);
  csr[pos] = src[e];
}

// GEMM: X[NN,128] fp32 @ W[128,ldw] (column slab of 64 via blockIdx.y),
// epilogue: Y[n,c] = bf16(dis[n] * acc). 64 rows x 64 cols per chunk,
// 256 threads, 4x4 register tile. LDS = 32KB W-slab + 32KB X-tile.
__global__ __launch_bounds__(256, 2) void k_gemm(const float* __restrict__ X,
    const float* __restrict__ W, int ldw, const float* __restrict__ dis,
    unsigned short* __restrict__ Y, int ldy, int nchunks){
  __shared__ float Wl[128 * 64];
  __shared__ float Xl[64 * 128];
  const int t = threadIdx.x;
  const int coff = blockIdx.y * 64;

  // stage W column-slab: Wl[k][c], c in [0,64)
  for (int i = t; i < 128 * 16; i += 256){
    int k = i >> 4, c4 = i & 15;
    ((float4*)Wl)[i] = *(const float4*)(W + (size_t)k * ldw + coff + (c4 << 2));
  }

  const int cg = t & 15;        // 16 col-groups * 4 cols = 64
  const int rg = t >> 4;        // 16 row-groups * 4 rows = 64
  float4* Xl4 = (float4*)Xl;
  const float4* Wl4 = (const float4*)Wl;

  for (int ch = blockIdx.x; ch < nchunks; ch += gridDim.x){
    const int R0 = ch * 64;
    __syncthreads();            // prev compute done (and W visible on iter 0)
    // stage X tile with XOR swizzle on k4 to break 512B-row bank aliasing
    for (int i = t; i < 64 * 32; i += 256){
      int r = i >> 5, k4 = i & 31;
      int gr = R0 + r;
      float4 v = make_float4(0.f, 0.f, 0.f, 0.f);
      if (gr < NN) v = ((const float4*)(X + (size_t)gr * 128))[k4];
      Xl4[(r << 5) | (k4 ^ (r & 3))] = v;
    }
    __syncthreads();

    float acc[4][4];
    #pragma unroll
    for (int r = 0; r < 4; r++)
      #pragma unroll
      for (int c = 0; c < 4; c++) acc[r][c] = 0.f;

    #pragma unroll 2
    for (int k4 = 0; k4 < 32; k4++){
      float4 xv[4], wv[4];
      #pragma unroll
      for (int r = 0; r < 4; r++)
        xv[r] = Xl4[(((rg << 2) + r) << 5) | (k4 ^ r)];
      #pragma unroll
      for (int kk = 0; kk < 4; kk++)
        wv[kk] = Wl4[((k4 << 2) + kk) * 16 + cg];
      const float* xs = (const float*)xv;
      const float* ws = (const float*)wv;
      #pragma unroll
      for (int kk = 0; kk < 4; kk++)
        #pragma unroll
        for (int r = 0; r < 4; r++)
          #pragma unroll
          for (int c = 0; c < 4; c++)
            acc[r][c] += xs[r * 4 + kk] * ws[kk * 4 + c];
    }

    const int rbase = R0 + (rg << 2);
    #pragma unroll
    for (int r = 0; r < 4; r++){
      int gr = rbase + r;
      if (gr < NN){
        float d = dis[gr];
        ushort4 o;
        o.x = f2bf(acc[r][0] * d);
        o.y = f2bf(acc[r][1] * d);
        o.z = f2bf(acc[r][2] * d);
        o.w = f2bf(acc[r][3] * d);
        *(ushort4*)(Y + (size_t)gr * ldy + coff + (cg << 2)) = o;
      }
    }
  }
}

// Aggregation: wave per node. out[n] = dn*(sum_{s in in(n)} y[s] + y[n]) + bias, opt relu.
template<int D, bool RELU>
__global__ __launch_bounds__(256) void k_agg(const unsigned short* __restrict__ Y,
    const int* __restrict__ rowstart, const int* __restrict__ cnt,
    const int* __restrict__ csr, const float* __restrict__ dis,
    const float* __restrict__ bias, float* __restrict__ OUT){
  const int wid = (blockIdx.x * 256 + threadIdx.x) >> 6;
  const int lane = threadIdx.x & 63;
  if (wid >= NN) return;
  const int n = wid;
  float acc0 = 0.f, acc1 = 0.f;
  if (D == 128){
    unsigned v = *(const unsigned*)(Y + (size_t)n * 128 + (lane << 1));
    acc0 = bf2f((unsigned short)(v & 0xffffu));
    acc1 = bf2f((unsigned short)(v >> 16));
  } else {
    acc0 = bf2f(Y[(size_t)n * 64 + lane]);
  }
  const int start = rowstart[n];
  const int end = start + cnt[n];
  int i = start;
  for (; i + 4 <= end; i += 4){
    int s0 = csr[i], s1 = csr[i + 1], s2 = csr[i + 2], s3 = csr[i + 3];
    if (D == 128){
      unsigned v0 = *(const unsigned*)(Y + (size_t)s0 * 128 + (lane << 1));
      unsigned v1 = *(const unsigned*)(Y + (size_t)s1 * 128 + (lane << 1));
      unsigned v2 = *(const unsigned*)(Y + (size_t)s2 * 128 + (lane << 1));
      unsigned v3 = *(const unsigned*)(Y + (size_t)s3 * 128 + (lane << 1));
      acc0 += bf2f((unsigned short)(v0 & 0xffffu)) + bf2f((unsigned short)(v1 & 0xffffu))
            + bf2f((unsigned short)(v2 & 0xffffu)) + bf2f((unsigned short)(v3 & 0xffffu));
      acc1 += bf2f((unsigned short)(v0 >> 16)) + bf2f((unsigned short)(v1 >> 16))
            + bf2f((unsigned short)(v2 >> 16)) + bf2f((unsigned short)(v3 >> 16));
    } else {
      acc0 += bf2f(Y[(size_t)s0 * 64 + lane]) + bf2f(Y[(size_t)s1 * 64 + lane])
            + bf2f(Y[(size_t)s2 * 64 + lane]) + bf2f(Y[(size_t)s3 * 64 + lane]);
    }
  }
  for (; i < end; ++i){
    int s = csr[i];
    if (D == 128){
      unsigned v = *(const unsigned*)(Y + (size_t)s * 128 + (lane << 1));
      acc0 += bf2f((unsigned short)(v & 0xffffu));
      acc1 += bf2f((unsigned short)(v >> 16));
    } else {
      acc0 += bf2f(Y[(size_t)s * 64 + lane]);
    }
  }
  const float dn = dis[n];
  if (D == 128){
    float o0 = dn * acc0 + bias[lane << 1];
    float o1 = dn * acc1 + bias[(lane << 1) + 1];
    if (RELU){ o0 = fmaxf(o0, 0.f); o1 = fmaxf(o1, 0.f); }
    *(float2*)(OUT + (size_t)n * 128 + (lane << 1)) = make_float2(o0, o1);
  } else {
    float o = dn * acc0 + bias[lane];
    if (RELU) o = fmaxf(o, 0.f);
    OUT[(size_t)n * 64 + lane] = o;
  }
}

extern "C" void kernel_launch(void* const* d_in, const int* in_sizes, int n_in,
                              void* d_out, int out_size, void* d_ws, size_t ws_size,
                              hipStream_t stream) {
  const float* x  = (const float*)d_in[0];
  const int*   ei = (const int*)d_in[1];
  const int*   src = ei;            // edge_index[0]
  const int*   dst = ei + NE;       // edge_index[1]
  const float* W1 = (const float*)d_in[2];
  const float* b1 = (const float*)d_in[3];
  const float* W2 = (const float*)d_in[4];
  const float* b2 = (const float*)d_in[5];
  float* out = (float*)d_out;

  char* w = (char*)d_ws;
  auto alloc = [&](size_t bytes){ void* p = (void*)w; w += (bytes + 255) & ~(size_t)255; return p; };
  int*   cnt      = (int*)alloc((size_t)NN * 4);
  int*   partial  = (int*)alloc((size_t)NN * 4);
  int*   blocksum = (int*)alloc(256 * 4);
  int*   rowstart = (int*)alloc((size_t)NN * 4);
  int*   cursor   = (int*)alloc((size_t)NN * 4);
  float* dis      = (float*)alloc((size_t)NN * 4);
  int*   csr      = (int*)alloc((size_t)NE * 4);
  unsigned short* y1 = (unsigned short*)alloc((size_t)NN * 128 * 2);
  float*          h  = (float*)alloc((size_t)NN * 128 * 4);
  unsigned short* y2 = (unsigned short*)alloc((size_t)NN * 64 * 2);

  const int NB_N = (NN + 255) / 256;   // 196
  const int NB_E = (NE + 255) / 256;   // 3125
  const int CHUNKS = (NN + 63) / 64;   // 782

  k_zero <<<NB_N, 256, 0, stream>>>(cnt);
  k_count<<<NB_E, 256, 0, stream>>>(dst, cnt);
  k_scan1<<<NB_N, 256, 0, stream>>>(cnt, partial, blocksum);
  k_scan2<<<1, 256, 0, stream>>>(blocksum, NB_N);
  k_scan3<<<NB_N, 256, 0, stream>>>(cnt, partial, blocksum, rowstart, cursor, dis);
  k_fill <<<NB_E, 256, 0, stream>>>(src, dst, cursor, csr);

  // layer 1: y1 = bf16(dis * (x @ W1)), two 64-col slabs
  k_gemm<<<dim3(512, 2), 256, 0, stream>>>(x, W1, 128, dis, y1, 128, CHUNKS);
  // h = relu(dis*(gather y1) + b1), fp32
  k_agg<128, true><<<(NN * 64 + 255) / 256, 256, 0, stream>>>(y1, rowstart, cnt, csr, dis, b1, h);
  // layer 2: y2 = bf16(dis * (h @ W2)), single 64-col slab
  k_gemm<<<dim3(512, 1), 256, 0, stream>>>(h, W2, 64, dis, y2, 64, CHUNKS);
  // out = dis*(gather y2) + b2
  k_agg<64, false><<<(NN * 64 + 255) / 256, 256, 0, stream>>>(y2, rowstart, cnt, csr, dis, b2, out);
}

// Round 3
// 246.329 us; speedup vs baseline: 1.2182x; 1.2182x over previous
//
#include <hip/hip_runtime.h>

#define NN 50000
#define NE 800000
#define NB 196          // ceil(50000/256) coarse buckets (256 nodes each)

static __device__ __forceinline__ float bf2f(unsigned short h){
  union { unsigned u; float f; } c; c.u = ((unsigned)h) << 16; return c.f;
}
static __device__ __forceinline__ unsigned short f2bf(float f){
  union { float f; unsigned u; } c; c.f = f;
  unsigned u = c.u;
  return (unsigned short)((u + 0x7fffu + ((u >> 16) & 1u)) >> 16);
}

__global__ void k_init0(int* __restrict__ btot){
  int t = threadIdx.x;
  if (t < NB) btot[t] = 0;
}

// histogram of dst>>8 into 196 bucket totals (LDS-staged)
__global__ __launch_bounds__(256) void k_bhist(const int* __restrict__ dst,
                                               int* __restrict__ btot){
  __shared__ int hh[NB];
  for (int i = threadIdx.x; i < NB; i += 256) hh[i] = 0;
  __syncthreads();
  int per = (NE + gridDim.x - 1) / gridDim.x;
  int e0 = blockIdx.x * per, e1 = min(e0 + per, NE);
  for (int e = e0 + threadIdx.x; e < e1; e += 256)
    atomicAdd(&hh[dst[e] >> 8], 1);
  __syncthreads();
  for (int i = threadIdx.x; i < NB; i += 256)
    if (hh[i]) atomicAdd(&btot[i], hh[i]);
}

// exclusive scan of bucket totals -> bases + cursors
__global__ void k_bscan(const int* __restrict__ btot, int* __restrict__ bbase,
                        int* __restrict__ gcur){
  __shared__ int sm[256];
  int t = threadIdx.x;
  int v = (t < NB) ? btot[t] : 0;
  sm[t] = v;
  __syncthreads();
  #pragma unroll
  for (int off = 1; off < 256; off <<= 1){
    int x = (t >= off) ? sm[t - off] : 0;
    __syncthreads();
    sm[t] += x;
    __syncthreads();
  }
  if (t < NB){ bbase[t] = sm[t] - v; gcur[t] = sm[t] - v; }
}

// multisplit, two-pass: count this block's edges per bucket, reserve one
// contiguous window per bucket, then scatter (src | dlow<<16) into the window.
// Every edge gets exactly one ticket -> exactly one store. No capacity paths.
__global__ __launch_bounds__(256) void k_bfill(const int* __restrict__ src,
    const int* __restrict__ dst, int* __restrict__ gcur, unsigned* __restrict__ stg){
  __shared__ int lcnt[NB];
  __shared__ int gbase[NB];
  for (int i = threadIdx.x; i < NB; i += 256) lcnt[i] = 0;
  __syncthreads();
  int per = (NE + gridDim.x - 1) / gridDim.x;
  int e0 = blockIdx.x * per, e1 = min(e0 + per, NE);
  // pass 1: count
  for (int e = e0 + threadIdx.x; e < e1; e += 256)
    atomicAdd(&lcnt[dst[e] >> 8], 1);
  __syncthreads();
  // reserve + reset (thread b owns bucket b; NB<=256)
  for (int b = threadIdx.x; b < NB; b += 256){
    gbase[b] = atomicAdd(&gcur[b], lcnt[b]);
    lcnt[b] = 0;
  }
  __syncthreads();
  // pass 2: scatter into reserved window (~16 edges -> 64B locality)
  for (int e = e0 + threadIdx.x; e < e1; e += 256){
    int d = dst[e];
    int b = d >> 8;
    unsigned entry = (unsigned)src[e] | (((unsigned)d & 255u) << 16);
    int pos = atomicAdd(&lcnt[b], 1);
    stg[gbase[b] + pos] = entry;
  }
}

// per-bucket: node histogram -> rowstart/cnt/dis, then direct scatter to csr
// (bucket csr segment is ~16KB -> stays in L2 during the scatter).
__global__ __launch_bounds__(256) void k_build(const unsigned* __restrict__ stg,
    const int* __restrict__ btot, const int* __restrict__ bbase,
    int* __restrict__ rowstart, int* __restrict__ cnt, float* __restrict__ dis,
    int* __restrict__ csr){
  __shared__ int lcnt[256];
  __shared__ int sm[256];
  const int b = blockIdx.x;
  const int t = threadIdx.x;
  const int ecnt = btot[b], ebase = bbase[b];
  lcnt[t] = 0;
  __syncthreads();
  for (int i = t; i < ecnt; i += 256){
    unsigned en = stg[ebase + i];
    atomicAdd(&lcnt[(en >> 16) & 255u], 1);
  }
  __syncthreads();
  int v = lcnt[t];
  sm[t] = v;
  __syncthreads();
  #pragma unroll
  for (int off = 1; off < 256; off <<= 1){
    int x = (t >= off) ? sm[t - off] : 0;
    __syncthreads();
    sm[t] += x;
    __syncthreads();
  }
  const int loff = sm[t] - v;     // exclusive within bucket
  const int node = (b << 8) + t;
  if (node < NN){
    rowstart[node] = ebase + loff;
    cnt[node] = v;
    dis[node] = rsqrtf((float)v + 1.0f);
  }
  __syncthreads();                // all lcnt reads (v) done before reuse
  lcnt[t] = loff;                 // reuse as cursor
  __syncthreads();
  for (int i = t; i < ecnt; i += 256){
    unsigned en = stg[ebase + i];
    int pos = atomicAdd(&lcnt[(en >> 16) & 255u], 1);
    csr[ebase + pos] = (int)(en & 0xffffu);
  }
}

// GEMM: X[NN,128] fp32 @ W[128,ldw] (64-col slab via blockIdx.y),
// epilogue: Y[n,c] = bf16(dis[n] * acc). 64x64 tile, 256 threads, 4x4 reg tile.
// X tile swizzle f=(k4+2*(row>>2))&31: the 4 row-group reads of one instr hit
// banks {0,8,16,24} (row stride 128 words == 0 mod 32 would alias otherwise).
__global__ __launch_bounds__(256, 2) void k_gemm(const float* __restrict__ X,
    const float* __restrict__ W, int ldw, const float* __restrict__ dis,
    unsigned short* __restrict__ Y, int ldy, int nchunks){
  __shared__ float Wl[128 * 64];
  __shared__ float Xl[64 * 128];
  const int t = threadIdx.x;
  const int coff = blockIdx.y * 64;

  for (int i = t; i < 128 * 16; i += 256){
    int k = i >> 4, c4 = i & 15;
    ((float4*)Wl)[i] = *(const float4*)(W + (size_t)k * ldw + coff + (c4 << 2));
  }

  const int cg = t & 15;
  const int rg = t >> 4;
  float4* Xl4 = (float4*)Xl;
  const float4* Wl4 = (const float4*)Wl;

  for (int ch = blockIdx.x; ch < nchunks; ch += gridDim.x){
    const int R0 = ch * 64;
    __syncthreads();
    for (int i = t; i < 64 * 32; i += 256){
      int r = i >> 5, k4 = i & 31;
      int gr = R0 + r;
      float4 v = make_float4(0.f, 0.f, 0.f, 0.f);
      if (gr < NN) v = ((const float4*)(X + (size_t)gr * 128))[k4];
      Xl4[(r << 5) | ((k4 + 2 * (r >> 2)) & 31)] = v;
    }
    __syncthreads();

    float acc[4][4];
    #pragma unroll
    for (int r = 0; r < 4; r++)
      #pragma unroll
      for (int c = 0; c < 4; c++) acc[r][c] = 0.f;

    #pragma unroll 2
    for (int k4 = 0; k4 < 32; k4++){
      float4 xv[4], wv[4];
      #pragma unroll
      for (int r = 0; r < 4; r++)
        xv[r] = Xl4[(((rg << 2) + r) << 5) | ((k4 + 2 * rg) & 31)];
      #pragma unroll
      for (int kk = 0; kk < 4; kk++)
        wv[kk] = Wl4[((k4 << 2) + kk) * 16 + cg];
      const float* xs = (const float*)xv;
      const float* ws = (const float*)wv;
      #pragma unroll
      for (int kk = 0; kk < 4; kk++)
        #pragma unroll
        for (int r = 0; r < 4; r++)
          #pragma unroll
          for (int c = 0; c < 4; c++)
            acc[r][c] += xs[r * 4 + kk] * ws[kk * 4 + c];
    }

    const int rbase = R0 + (rg << 2);
    #pragma unroll
    for (int r = 0; r < 4; r++){
      int gr = rbase + r;
      if (gr < NN){
        float d = dis[gr];
        ushort4 o;
        o.x = f2bf(acc[r][0] * d);
        o.y = f2bf(acc[r][1] * d);
        o.z = f2bf(acc[r][2] * d);
        o.w = f2bf(acc[r][3] * d);
        *(ushort4*)(Y + (size_t)gr * ldy + coff + (cg << 2)) = o;
      }
    }
  }
}

// Aggregation: wave per node. out[n] = dn*(sum_{s in in(n)} y[s] + y[n]) + bias, opt relu.
template<int D, bool RELU>
__global__ __launch_bounds__(256) void k_agg(const unsigned short* __restrict__ Y,
    const int* __restrict__ rowstart, const int* __restrict__ cnt,
    const int* __restrict__ csr, const float* __restrict__ dis,
    const float* __restrict__ bias, float* __restrict__ OUT){
  const int wid = (blockIdx.x * 256 + threadIdx.x) >> 6;
  const int lane = threadIdx.x & 63;
  if (wid >= NN) return;
  const int n = wid;
  float acc0 = 0.f, acc1 = 0.f;
  if (D == 128){
    unsigned v = *(const unsigned*)(Y + (size_t)n * 128 + (lane << 1));
    acc0 = bf2f((unsigned short)(v & 0xffffu));
    acc1 = bf2f((unsigned short)(v >> 16));
  } else {
    acc0 = bf2f(Y[(size_t)n * 64 + lane]);
  }
  const int start = rowstart[n];
  const int end = start + cnt[n];
  int i = start;
  for (; i + 4 <= end; i += 4){
    int s0 = csr[i], s1 = csr[i + 1], s2 = csr[i + 2], s3 = csr[i + 3];
    if (D == 128){
      unsigned v0 = *(const unsigned*)(Y + (size_t)s0 * 128 + (lane << 1));
      unsigned v1 = *(const unsigned*)(Y + (size_t)s1 * 128 + (lane << 1));
      unsigned v2 = *(const unsigned*)(Y + (size_t)s2 * 128 + (lane << 1));
      unsigned v3 = *(const unsigned*)(Y + (size_t)s3 * 128 + (lane << 1));
      acc0 += bf2f((unsigned short)(v0 & 0xffffu)) + bf2f((unsigned short)(v1 & 0xffffu))
            + bf2f((unsigned short)(v2 & 0xffffu)) + bf2f((unsigned short)(v3 & 0xffffu));
      acc1 += bf2f((unsigned short)(v0 >> 16)) + bf2f((unsigned short)(v1 >> 16))
            + bf2f((unsigned short)(v2 >> 16)) + bf2f((unsigned short)(v3 >> 16));
    } else {
      acc0 += bf2f(Y[(size_t)s0 * 64 + lane]) + bf2f(Y[(size_t)s1 * 64 + lane])
            + bf2f(Y[(size_t)s2 * 64 + lane]) + bf2f(Y[(size_t)s3 * 64 + lane]);
    }
  }
  for (; i < end; ++i){
    int s = csr[i];
    if (D == 128){
      unsigned v = *(const unsigned*)(Y + (size_t)s * 128 + (lane << 1));
      acc0 += bf2f((unsigned short)(v & 0xffffu));
      acc1 += bf2f((unsigned short)(v >> 16));
    } else {
      acc0 += bf2f(Y[(size_t)s * 64 + lane]);
    }
  }
  const float dn = dis[n];
  if (D == 128){
    float o0 = dn * acc0 + bias[lane << 1];
    float o1 = dn * acc1 + bias[(lane << 1) + 1];
    if (RELU){ o0 = fmaxf(o0, 0.f); o1 = fmaxf(o1, 0.f); }
    *(float2*)(OUT + (size_t)n * 128 + (lane << 1)) = make_float2(o0, o1);
  } else {
    float o = dn * acc0 + bias[lane];
    if (RELU) o = fmaxf(o, 0.f);
    OUT[(size_t)n * 64 + lane] = o;
  }
}

extern "C" void kernel_launch(void* const* d_in, const int* in_sizes, int n_in,
                              void* d_out, int out_size, void* d_ws, size_t ws_size,
                              hipStream_t stream) {
  const float* x  = (const float*)d_in[0];
  const int*   ei = (const int*)d_in[1];
  const int*   src = ei;
  const int*   dst = ei + NE;
  const float* W1 = (const float*)d_in[2];
  const float* b1 = (const float*)d_in[3];
  const float* W2 = (const float*)d_in[4];
  const float* b2 = (const float*)d_in[5];
  float* out = (float*)d_out;

  char* w = (char*)d_ws;
  auto alloc = [&](size_t bytes){ void* p = (void*)w; w += (bytes + 255) & ~(size_t)255; return p; };
  int*   btot     = (int*)alloc(NB * 4);
  int*   bbase    = (int*)alloc(NB * 4);
  int*   gcur     = (int*)alloc(NB * 4);
  int*   rowstart = (int*)alloc((size_t)NN * 4);
  int*   cnt      = (int*)alloc((size_t)NN * 4);
  float* dis      = (float*)alloc((size_t)NN * 4);
  int*   csr      = (int*)alloc((size_t)NE * 4);
  unsigned short* y1 = (unsigned short*)alloc((size_t)NN * 128 * 2);
  float*          h  = (float*)alloc((size_t)NN * 128 * 4);
  unsigned short* y2 = (unsigned short*)alloc((size_t)NN * 64 * 2);
  // stg (NE*4 = 3.2MB) aliases y2's region (6.4MB): stg is dead after k_build,
  // y2 is first written by the layer-2 gemm which runs after k_build.
  unsigned* stg = (unsigned*)y2;

  const int CHUNKS = (NN + 63) / 64;   // 782

  k_init0<<<1, 256, 0, stream>>>(btot);
  k_bhist<<<256, 256, 0, stream>>>(dst, btot);
  k_bscan<<<1, 256, 0, stream>>>(btot, bbase, gcur);
  k_bfill<<<256, 256, 0, stream>>>(src, dst, gcur, stg);
  k_build<<<NB, 256, 0, stream>>>(stg, btot, bbase, rowstart, cnt, dis, csr);

  k_gemm<<<dim3(CHUNKS, 2), 256, 0, stream>>>(x, W1, 128, dis, y1, 128, CHUNKS);
  k_agg<128, true><<<(NN * 64 + 255) / 256, 256, 0, stream>>>(y1, rowstart, cnt, csr, dis, b1, h);
  k_gemm<<<dim3(CHUNKS, 1), 256, 0, stream>>>(h, W2, 64, dis, y2, 64, CHUNKS);
  k_agg<64, false><<<(NN * 64 + 255) / 256, 256, 0, stream>>>(y2, rowstart, cnt, csr, dis, b2, out);
}

// Round 4
// 237.052 us; speedup vs baseline: 1.2659x; 1.0391x over previous
//
#include <hip/hip_runtime.h>

#define NN 50000
#define NE 800000
#define NB 196          // ceil(50000/256) coarse buckets (256 nodes each)
#define KPAD 136        // 128 + 8 bf16 pad: B-frag b128 reads -> 2-way bank alias (free)

typedef __bf16 bf16x8 __attribute__((ext_vector_type(8)));
typedef float  f32x4  __attribute__((ext_vector_type(4)));

static __device__ __forceinline__ float bf2f(unsigned short h){
  union { unsigned u; float f; } c; c.u = ((unsigned)h) << 16; return c.f;
}
static __device__ __forceinline__ unsigned short f2bf(float f){
  union { float f; unsigned u; } c; c.f = f;
  unsigned u = c.u;
  return (unsigned short)((u + 0x7fffu + ((u >> 16) & 1u)) >> 16);
}

__global__ void k_init0(int* __restrict__ btot){
  int t = threadIdx.x;
  if (t < NB) btot[t] = 0;
}

__global__ __launch_bounds__(256) void k_bhist(const int* __restrict__ dst,
                                               int* __restrict__ btot){
  __shared__ int hh[NB];
  for (int i = threadIdx.x; i < NB; i += 256) hh[i] = 0;
  __syncthreads();
  int per = (NE + gridDim.x - 1) / gridDim.x;
  int e0 = blockIdx.x * per, e1 = min(e0 + per, NE);
  for (int e = e0 + threadIdx.x; e < e1; e += 256)
    atomicAdd(&hh[dst[e] >> 8], 1);
  __syncthreads();
  for (int i = threadIdx.x; i < NB; i += 256)
    if (hh[i]) atomicAdd(&btot[i], hh[i]);
}

__global__ void k_bscan(const int* __restrict__ btot, int* __restrict__ bbase,
                        int* __restrict__ gcur){
  __shared__ int sm[256];
  int t = threadIdx.x;
  int v = (t < NB) ? btot[t] : 0;
  sm[t] = v;
  __syncthreads();
  #pragma unroll
  for (int off = 1; off < 256; off <<= 1){
    int x = (t >= off) ? sm[t - off] : 0;
    __syncthreads();
    sm[t] += x;
    __syncthreads();
  }
  if (t < NB){ bbase[t] = sm[t] - v; gcur[t] = sm[t] - v; }
}

// two-pass multisplit: exactly one ticket -> one store per edge.
__global__ __launch_bounds__(256) void k_bfill(const int* __restrict__ src,
    const int* __restrict__ dst, int* __restrict__ gcur, unsigned* __restrict__ stg){
  __shared__ int lcnt[NB];
  __shared__ int gbase[NB];
  for (int i = threadIdx.x; i < NB; i += 256) lcnt[i] = 0;
  __syncthreads();
  int per = (NE + gridDim.x - 1) / gridDim.x;
  int e0 = blockIdx.x * per, e1 = min(e0 + per, NE);
  for (int e = e0 + threadIdx.x; e < e1; e += 256)
    atomicAdd(&lcnt[dst[e] >> 8], 1);
  __syncthreads();
  for (int b = threadIdx.x; b < NB; b += 256){
    gbase[b] = atomicAdd(&gcur[b], lcnt[b]);
    lcnt[b] = 0;
  }
  __syncthreads();
  for (int e = e0 + threadIdx.x; e < e1; e += 256){
    int d = dst[e];
    int b = d >> 8;
    unsigned entry = (unsigned)src[e] | (((unsigned)d & 255u) << 16);
    int pos = atomicAdd(&lcnt[b], 1);
    stg[gbase[b] + pos] = entry;
  }
}

__global__ __launch_bounds__(256) void k_build(const unsigned* __restrict__ stg,
    const int* __restrict__ btot, const int* __restrict__ bbase,
    int* __restrict__ rowstart, int* __restrict__ cnt, float* __restrict__ dis,
    int* __restrict__ csr){
  __shared__ int lcnt[256];
  __shared__ int sm[256];
  const int b = blockIdx.x;
  const int t = threadIdx.x;
  const int ecnt = btot[b], ebase = bbase[b];
  lcnt[t] = 0;
  __syncthreads();
  for (int i = t; i < ecnt; i += 256){
    unsigned en = stg[ebase + i];
    atomicAdd(&lcnt[(en >> 16) & 255u], 1);
  }
  __syncthreads();
  int v = lcnt[t];
  sm[t] = v;
  __syncthreads();
  #pragma unroll
  for (int off = 1; off < 256; off <<= 1){
    int x = (t >= off) ? sm[t - off] : 0;
    __syncthreads();
    sm[t] += x;
    __syncthreads();
  }
  const int loff = sm[t] - v;
  const int node = (b << 8) + t;
  if (node < NN){
    rowstart[node] = ebase + loff;
    cnt[node] = v;
    dis[node] = rsqrtf((float)v + 1.0f);
  }
  __syncthreads();
  lcnt[t] = loff;
  __syncthreads();
  for (int i = t; i < ecnt; i += 256){
    unsigned en = stg[ebase + i];
    int pos = atomicAdd(&lcnt[(en >> 16) & 255u], 1);
    csr[ebase + pos] = (int)(en & 0xffffu);
  }
}

// split fp32 -> (hi,lo) bf16 pair; x = hi + lo to ~2^-17 rel
__global__ __launch_bounds__(256) void k_split(const float* __restrict__ X,
    unsigned short* __restrict__ xh, unsigned short* __restrict__ xl, int n4){
  int i = blockIdx.x * 256 + threadIdx.x;
  if (i >= n4) return;
  float4 v = ((const float4*)X)[i];
  ushort4 h, l;
  h.x = f2bf(v.x); l.x = f2bf(v.x - bf2f(h.x));
  h.y = f2bf(v.y); l.y = f2bf(v.y - bf2f(h.y));
  h.z = f2bf(v.z); l.z = f2bf(v.z - bf2f(h.z));
  h.w = f2bf(v.w); l.w = f2bf(v.w - bf2f(h.w));
  ((ushort4*)xh)[i] = h;
  ((ushort4*)xl)[i] = l;
}

// W -> per-slab [n][KPAD] hi/lo bf16. slab 0: W1 cols 0..63, 1: W1 cols 64..127,
// 2: W2 cols 0..63. wbuf layout: [slab][hi 64*KPAD][lo 64*KPAD]
__global__ __launch_bounds__(256) void k_prep(const float* __restrict__ W1,
    const float* __restrict__ W2, unsigned short* __restrict__ wbuf){
  int s = blockIdx.x;
  const float* W = (s < 2) ? W1 : W2;
  int ldw = (s < 2) ? 128 : 64;
  int coff = (s == 1) ? 64 : 0;
  unsigned short* wh = wbuf + (size_t)s * 2 * 64 * KPAD;
  unsigned short* wl = wh + 64 * KPAD;
  for (int i = threadIdx.x; i < 128 * 64; i += 256){
    int k = i >> 6, n = i & 63;
    float v = W[(size_t)k * ldw + coff + n];
    unsigned short h = f2bf(v);
    unsigned short l = f2bf(v - bf2f(h));
    wh[n * KPAD + k] = h;
    wl[n * KPAD + k] = l;
  }
}

// MFMA GEMM: C[64rows x 64cols] per block = (Ah+Al)[64,128] @ (Bh+Bl)[128,64],
// 3 products hi*hi + hi*lo + lo*hi (lo*lo ~2^-18, dropped).
// A frags straight from global (already in MFMA lane layout); B slab in LDS.
// Epilogue: Y[r][coff+c] = bf16(dis[r] * acc).
__global__ __launch_bounds__(256, 4) void k_gemm(
    const unsigned short* __restrict__ Ah, const unsigned short* __restrict__ Al,
    const unsigned short* __restrict__ Wpre, const float* __restrict__ dis,
    unsigned short* __restrict__ Y, int ldy){
  __shared__ unsigned short Bh[64 * KPAD];
  __shared__ unsigned short Bl[64 * KPAD];
  const int t = threadIdx.x;
  const unsigned short* Wsl = Wpre + (size_t)blockIdx.y * 2 * 64 * KPAD;
  {  // 64*KPAD ushorts = 1088 uint4 per array
    const uint4* s4 = (const uint4*)Wsl;
    uint4* bh4 = (uint4*)Bh;
    uint4* bl4 = (uint4*)Bl;
    for (int i = t; i < 1088; i += 256) bh4[i] = s4[i];
    for (int i = t; i < 1088; i += 256) bl4[i] = s4[1088 + i];
  }
  __syncthreads();

  const int wv = t >> 6;
  const int lane = t & 63;
  const int m = lane & 15;       // A row / D col / B col
  const int quad = lane >> 4;    // k-group
  const int R0 = blockIdx.x * 64;
  const int coff = blockIdx.y * 64;
  const int row = R0 + wv * 16 + m;
  const int rowc = min(row, NN - 1);
  const unsigned short* pAh = Ah + (size_t)rowc * 128 + quad * 8;
  const unsigned short* pAl = Al + (size_t)rowc * 128 + quad * 8;

  f32x4 acc[4];
  #pragma unroll
  for (int tt = 0; tt < 4; tt++) acc[tt] = (f32x4){0.f, 0.f, 0.f, 0.f};

  #pragma unroll
  for (int ki = 0; ki < 4; ki++){
    bf16x8 ah = *(const bf16x8*)(pAh + ki * 32);
    bf16x8 al = *(const bf16x8*)(pAl + ki * 32);
    #pragma unroll
    for (int tt = 0; tt < 4; tt++){
      const int off = (tt * 16 + m) * KPAD + ki * 32 + quad * 8;
      bf16x8 bh = *(const bf16x8*)(Bh + off);
      bf16x8 bl = *(const bf16x8*)(Bl + off);
      acc[tt] = __builtin_amdgcn_mfma_f32_16x16x32_bf16(ah, bh, acc[tt], 0, 0, 0);
      acc[tt] = __builtin_amdgcn_mfma_f32_16x16x32_bf16(ah, bl, acc[tt], 0, 0, 0);
      acc[tt] = __builtin_amdgcn_mfma_f32_16x16x32_bf16(al, bh, acc[tt], 0, 0, 0);
    }
  }

  const int orow = R0 + wv * 16 + quad * 4;   // D row = quad*4 + reg
  #pragma unroll
  for (int r = 0; r < 4; r++){
    int gr = orow + r;
    if (gr < NN){
      float dsc = dis[gr];
      #pragma unroll
      for (int tt = 0; tt < 4; tt++)
        Y[(size_t)gr * ldy + coff + tt * 16 + m] = f2bf(acc[tt][r] * dsc);
    }
  }
}

// Aggregation: wave per node. o = dn*(sum_in y[s] + y[n]) + bias, opt relu.
// SPLIT: write (hi,lo) bf16 pair (for next MFMA layer); else fp32 out.
template<int D, bool RELU, bool SPLIT>
__global__ __launch_bounds__(256) void k_agg(const unsigned short* __restrict__ Y,
    const int* __restrict__ rowstart, const int* __restrict__ cnt,
    const int* __restrict__ csr, const float* __restrict__ dis,
    const float* __restrict__ bias, float* __restrict__ OUT,
    unsigned short* __restrict__ OH, unsigned short* __restrict__ OL){
  const int wid = (blockIdx.x * 256 + threadIdx.x) >> 6;
  const int lane = threadIdx.x & 63;
  if (wid >= NN) return;
  const int n = wid;
  float acc0 = 0.f, acc1 = 0.f;
  if (D == 128){
    unsigned v = *(const unsigned*)(Y + (size_t)n * 128 + (lane << 1));
    acc0 = bf2f((unsigned short)(v & 0xffffu));
    acc1 = bf2f((unsigned short)(v >> 16));
  } else {
    acc0 = bf2f(Y[(size_t)n * 64 + lane]);
  }
  const int start = rowstart[n];
  const int end = start + cnt[n];
  int i = start;
  for (; i + 4 <= end; i += 4){
    int s0 = csr[i], s1 = csr[i + 1], s2 = csr[i + 2], s3 = csr[i + 3];
    if (D == 128){
      unsigned v0 = *(const unsigned*)(Y + (size_t)s0 * 128 + (lane << 1));
      unsigned v1 = *(const unsigned*)(Y + (size_t)s1 * 128 + (lane << 1));
      unsigned v2 = *(const unsigned*)(Y + (size_t)s2 * 128 + (lane << 1));
      unsigned v3 = *(const unsigned*)(Y + (size_t)s3 * 128 + (lane << 1));
      acc0 += bf2f((unsigned short)(v0 & 0xffffu)) + bf2f((unsigned short)(v1 & 0xffffu))
            + bf2f((unsigned short)(v2 & 0xffffu)) + bf2f((unsigned short)(v3 & 0xffffu));
      acc1 += bf2f((unsigned short)(v0 >> 16)) + bf2f((unsigned short)(v1 >> 16))
            + bf2f((unsigned short)(v2 >> 16)) + bf2f((unsigned short)(v3 >> 16));
    } else {
      acc0 += bf2f(Y[(size_t)s0 * 64 + lane]) + bf2f(Y[(size_t)s1 * 64 + lane])
            + bf2f(Y[(size_t)s2 * 64 + lane]) + bf2f(Y[(size_t)s3 * 64 + lane]);
    }
  }
  for (; i < end; ++i){
    int s = csr[i];
    if (D == 128){
      unsigned v = *(const unsigned*)(Y + (size_t)s * 128 + (lane << 1));
      acc0 += bf2f((unsigned short)(v & 0xffffu));
      acc1 += bf2f((unsigned short)(v >> 16));
    } else {
      acc0 += bf2f(Y[(size_t)s * 64 + lane]);
    }
  }
  const float dn = dis[n];
  if (D == 128){
    float o0 = dn * acc0 + bias[lane << 1];
    float o1 = dn * acc1 + bias[(lane << 1) + 1];
    if (RELU){ o0 = fmaxf(o0, 0.f); o1 = fmaxf(o1, 0.f); }
    if (SPLIT){
      unsigned short h0 = f2bf(o0), h1 = f2bf(o1);
      unsigned short l0 = f2bf(o0 - bf2f(h0)), l1 = f2bf(o1 - bf2f(h1));
      *(unsigned*)(OH + (size_t)n * 128 + (lane << 1)) = (unsigned)h0 | ((unsigned)h1 << 16);
      *(unsigned*)(OL + (size_t)n * 128 + (lane << 1)) = (unsigned)l0 | ((unsigned)l1 << 16);
    } else {
      *(float2*)(OUT + (size_t)n * 128 + (lane << 1)) = make_float2(o0, o1);
    }
  } else {
    float o = dn * acc0 + bias[lane];
    if (RELU) o = fmaxf(o, 0.f);
    OUT[(size_t)n * 64 + lane] = o;
  }
}

extern "C" void kernel_launch(void* const* d_in, const int* in_sizes, int n_in,
                              void* d_out, int out_size, void* d_ws, size_t ws_size,
                              hipStream_t stream) {
  const float* x  = (const float*)d_in[0];
  const int*   ei = (const int*)d_in[1];
  const int*   src = ei;
  const int*   dst = ei + NE;
  const float* W1 = (const float*)d_in[2];
  const float* b1 = (const float*)d_in[3];
  const float* W2 = (const float*)d_in[4];
  const float* b2 = (const float*)d_in[5];
  float* out = (float*)d_out;

  char* w = (char*)d_ws;
  auto alloc = [&](size_t bytes){ void* p = (void*)w; w += (bytes + 255) & ~(size_t)255; return p; };
  int*   btot     = (int*)alloc(NB * 4);
  int*   bbase    = (int*)alloc(NB * 4);
  int*   gcur     = (int*)alloc(NB * 4);
  int*   rowstart = (int*)alloc((size_t)NN * 4);
  int*   cnt      = (int*)alloc((size_t)NN * 4);
  float* dis      = (float*)alloc((size_t)NN * 4);
  int*   csr      = (int*)alloc((size_t)NE * 4);
  unsigned short* xh = (unsigned short*)alloc((size_t)NN * 128 * 2);
  unsigned short* xl = (unsigned short*)alloc((size_t)NN * 128 * 2);
  unsigned short* hh = (unsigned short*)alloc((size_t)NN * 128 * 2);
  unsigned short* hl = (unsigned short*)alloc((size_t)NN * 128 * 2);
  unsigned short* y1 = (unsigned short*)alloc((size_t)NN * 128 * 2);
  unsigned short* y2 = (unsigned short*)alloc((size_t)NN * 64 * 2);
  unsigned short* wbuf = (unsigned short*)alloc((size_t)3 * 2 * 64 * KPAD * 2);
  // stg (NE*4 = 3.2MB) aliases y2 region (6.4MB): stg dead after k_build,
  // y2 first written by layer-2 gemm (after k_build).
  unsigned* stg = (unsigned*)y2;

  const int CHUNKS = (NN + 63) / 64;   // 782

  k_init0<<<1, 256, 0, stream>>>(btot);
  k_bhist<<<256, 256, 0, stream>>>(dst, btot);
  k_bscan<<<1, 256, 0, stream>>>(btot, bbase, gcur);
  k_bfill<<<256, 256, 0, stream>>>(src, dst, gcur, stg);
  k_build<<<NB, 256, 0, stream>>>(stg, btot, bbase, rowstart, cnt, dis, csr);

  k_split<<<(NN * 128 / 4 + 255) / 256, 256, 0, stream>>>(x, xh, xl, NN * 128 / 4);
  k_prep<<<3, 256, 0, stream>>>(W1, W2, wbuf);

  k_gemm<<<dim3(CHUNKS, 2), 256, 0, stream>>>(xh, xl, wbuf, dis, y1, 128);
  k_agg<128, true, true><<<(NN * 64 + 255) / 256, 256, 0, stream>>>(
      y1, rowstart, cnt, csr, dis, b1, nullptr, hh, hl);
  k_gemm<<<dim3(CHUNKS, 1), 256, 0, stream>>>(hh, hl, wbuf + (size_t)2 * 2 * 64 * KPAD, dis, y2, 64);
  k_agg<64, false, false><<<(NN * 64 + 255) / 256, 256, 0, stream>>>(
      y2, rowstart, cnt, csr, dis, b2, out, nullptr, nullptr);
}